// Round 15
// baseline (119.718 us; speedup 1.0000x reference)
//
#include <hip/hip_runtime.h>
#include <hip/hip_cooperative_groups.h>

namespace cg = cooperative_groups;

// SpMM: out[b,m] = bias[m] + sum_{e: dst[e]==m} values[e] * x[b, src[e]]
// B=32, N=M=50000, E=1600000.
// v15 (from v14=118.9us; ~46us = harness workspace fill, fixed tax).
// All three phases need exactly NB=391 blocks at this shape and co-reside at
// 2 blocks/CU (69.7KB LDS) -> fuse zero+tx+bin+sort_gather into ONE
// cooperative kernel with two grid.sync()s. Phase bodies identical to v14's
// proven kernels; occupancy-gated with full fallback to the v14 4-dispatch
// path (and the atomic path for odd shapes).

#define BATCH 32
#define DPB   128             // dsts per bucket -> NB = 391
#define NB_MAX 400
#define BIN_TPB 1024
#define BIN_CHUNK 4096
#define CAPB  5120            // per-bucket sv segment capacity (entries)
#define CAP   5120            // sort_gather LDS tile (entries) >= CAPB
#define SMEM_BYTES 69664      // union of phase LDS layouts (C is largest)

// ============================ mega kernel ============================
__global__ __launch_bounds__(1024, 8) void k_mega(
    const float* __restrict__ x, float* __restrict__ xt,
    const int* __restrict__ idx, const float* __restrict__ values,
    int* __restrict__ gcursor, int2* __restrict__ sv,
    const float* __restrict__ bias, float* __restrict__ out,
    int N, int E, int M, int NB) {
    __shared__ alignas(16) char smem[SMEM_BYTES];
    cg::grid_group grid = cg::this_grid();
    const int tid = threadIdx.x;
    const int bid = blockIdx.x;
    const int NG  = gridDim.x;

    // ---- Phase A: transpose x (B,N)->(N,B), 4 sub-tiles/block; zero gcursor ----
    {
        float (*tile)[32][33] = reinterpret_cast<float(*)[32][33]>(smem); // 16.9KB
        if (bid == 0 && tid < NB) gcursor[tid] = 0;
        const int sub = tid >> 8;         // 0..3
        const int t2  = tid & 255;
        const int tx  = t2 & 31;
        const int ty  = t2 >> 5;          // 0..7
        const int TBt = (N + 31) / 32;
        for (int base = bid * 4; base < TBt; base += NG * 4) {
            const int tb = base + sub;
            const int n0 = tb * 32;
            #pragma unroll
            for (int k = 0; k < 4; ++k) {
                const int b = ty + 8 * k;
                const int n = n0 + tx;
                tile[sub][tx][b] = (tb < TBt && n < N) ? x[(size_t)b * N + n] : 0.0f;
            }
            __syncthreads();
            #pragma unroll
            for (int k = 0; k < 4; ++k) {
                const int n = n0 + ty + 8 * k;
                if (tb < TBt && n < N) xt[(size_t)n * BATCH + tx] = tile[sub][ty + 8 * k][tx];
            }
            __syncthreads();
        }
    }
    __threadfence();
    grid.sync();
    __threadfence();

    // ---- Phase B: bin (LDS counting-sort per chunk, coalesced write-out) ----
    {
        int*  hist  = (int*)(smem);
        int*  loff  = (int*)(smem + 1600);
        int*  gbase = (int*)(smem + 3200);
        int*  gcap  = (int*)(smem + 4800);
        int2* svl   = (int2*)(smem + 6400);
        int*  gidx  = (int*)(smem + 39168);
        const int nchunks = (E + BIN_CHUNK - 1) / BIN_CHUNK;
        for (int ch = bid; ch < nchunks; ch += NG) {
            const int c0 = ch * BIN_CHUNK;
            const int nE = min(BIN_CHUNK, E - c0);
            if (tid < NB) hist[tid] = 0;
            __syncthreads();
            const int e0 = c0 + (tid << 2);
            const bool v4 = ((E & 3) == 0) && (e0 + 3 < E);
            int d[4] = {-1, -1, -1, -1};
            if (v4) {
                const int4 d4 = *(const int4*)(idx + E + e0);
                d[0] = d4.x; d[1] = d4.y; d[2] = d4.z; d[3] = d4.w;
            } else {
                #pragma unroll
                for (int k = 0; k < 4; ++k) if (e0 + k < E) d[k] = idx[E + e0 + k];
            }
            #pragma unroll
            for (int k = 0; k < 4; ++k) if (d[k] >= 0) atomicAdd(&hist[d[k] >> 7], 1);
            __syncthreads();
            if (tid < 64) {   // wave 0: exclusive scan of chunk counts -> loff
                int carry = 0;
                for (int c = 0; c < NB; c += 64) {
                    const int j = c + tid;
                    const int v = (j < NB) ? hist[j] : 0;
                    int inc = v;
                    #pragma unroll
                    for (int dlt = 1; dlt < 64; dlt <<= 1) {
                        const int t = __shfl_up(inc, dlt, 64);
                        if (tid >= dlt) inc += t;
                    }
                    if (j < NB) loff[j] = carry + inc - v;
                    carry += __shfl(inc, 63, 64);
                }
            }
            __syncthreads();
            if (tid < NB) {
                const int c = hist[tid];
                if (c) {
                    const int old = atomicAdd(&gcursor[tid], c);
                    gbase[tid] = tid * CAPB + old;
                    gcap[tid]  = CAPB - old;
                } else {
                    gbase[tid] = 0;
                    gcap[tid]  = 0;
                }
                hist[tid] = 0;
            }
            __syncthreads();
            int   s[4];
            float vv[4];
            if (v4) {
                const int4   s4  = *(const int4*)(idx + e0);
                const float4 v4v = *(const float4*)(values + e0);
                s[0] = s4.x; s[1] = s4.y; s[2] = s4.z; s[3] = s4.w;
                vv[0] = v4v.x; vv[1] = v4v.y; vv[2] = v4v.z; vv[3] = v4v.w;
            } else {
                #pragma unroll
                for (int k = 0; k < 4; ++k) {
                    if (e0 + k < E) { s[k] = idx[e0 + k]; vv[k] = values[e0 + k]; }
                    else { s[k] = 0; vv[k] = 0.0f; }
                }
            }
            #pragma unroll
            for (int k = 0; k < 4; ++k) {
                if (d[k] >= 0) {
                    const int bkt = d[k] >> 7;
                    const int off = atomicAdd(&hist[bkt], 1);
                    const int slot = loff[bkt] + off;
                    const int packed = (s[k] & 0xFFFF) | ((d[k] & 127) << 16);
                    svl[slot]  = make_int2(packed, __float_as_int(vv[k]));
                    gidx[slot] = (off < gcap[bkt]) ? (gbase[bkt] + off) : -1;
                }
            }
            __syncthreads();
            for (int q = tid; q < nE; q += BIN_TPB) {
                const int gi = gidx[q];
                if (gi >= 0) sv[gi] = svl[q];
            }
            __syncthreads();   // protect hist/svl reuse next chunk
        }
    }
    __threadfence();
    grid.sync();
    __threadfence();

    // ---- Phase C: fused sort+gather per bucket ----
    {
        int2* stage = (int2*)(smem);                          // 40960 B
        unsigned short* perm = (unsigned short*)(smem + 40960); // 10240 B
        int* cnt = (int*)(smem + 51200);
        int* off = (int*)(smem + 51712);                      // DPB+1 ints
        int* cur = (int*)(smem + 52232);
        float (*tile)[33] = (float(*)[33])(smem + 52744);     // 16896 B

        const int w    = tid >> 6;    // wave 0..15
        const int lane = tid & 63;
        const int g    = lane >> 3;   // 0..7 edge slot
        const int j    = lane & 7;    // 16B slice of the 128B xt row
        const float4* __restrict__ xt4 = (const float4*)xt;

        for (int bkt = bid; bkt < NB; bkt += NG) {
            const int m0  = bkt * DPB;
            const int beg = bkt * CAPB;
            const int end = beg + min(gcursor[bkt], CAPB);

            for (int i = tid; i < DPB * 33; i += 1024) ((float*)tile)[i] = 0.0f;

            for (int t0 = beg; t0 < end; t0 += CAP) {
                const int nE = min(CAP, end - t0);
                __syncthreads();            // tile ready / prev tile consumed
                if (tid < DPB) cnt[tid] = 0;
                __syncthreads();
                // stage load (int4 = 2 entries) + row count; t0 always even
                const int npair = nE >> 1;
                const int4* __restrict__ sv4 = (const int4*)(sv + t0);
                for (int p = tid; p < npair; p += 1024) {
                    const int4 q = sv4[p];
                    const int i0 = p << 1;
                    stage[i0]     = make_int2(q.x, q.y);
                    stage[i0 + 1] = make_int2(q.z, q.w);
                    atomicAdd(&cnt[(q.x >> 16) & 127], 1);
                    atomicAdd(&cnt[(q.z >> 16) & 127], 1);
                }
                if ((nE & 1) && tid == 1023) {
                    const int i0 = npair << 1;
                    const int2 a = sv[t0 + i0];
                    stage[i0] = a;
                    atomicAdd(&cnt[(a.x >> 16) & 127], 1);
                }
                __syncthreads();
                if (tid < 64) {   // wave 0: scan 128 counts
                    int carry = 0;
                    #pragma unroll
                    for (int c = 0; c < DPB; c += 64) {
                        const int jj = c + tid;
                        const int v = cnt[jj];
                        int inc = v;
                        #pragma unroll
                        for (int dlt = 1; dlt < 64; dlt <<= 1) {
                            const int t = __shfl_up(inc, dlt, 64);
                            if (tid >= dlt) inc += t;
                        }
                        off[jj] = carry + inc - v;
                        cur[jj] = carry + inc - v;
                        carry += __shfl(inc, 63, 64);
                    }
                    if (tid == 0) off[DPB] = carry;
                }
                __syncthreads();
                for (int i = tid; i < nE; i += 1024) {
                    const int dl = (stage[i].x >> 16) & 127;
                    const int p = atomicAdd(&cur[dl], 1);
                    perm[p] = (unsigned short)i;
                }
                __syncthreads();
                #pragma unroll
                for (int k = 0; k < DPB / 16; ++k) {
                    const int r  = w + 16 * k;
                    const int rb = off[r];
                    const int re = off[r + 1];
                    float ax = 0.f, ay = 0.f, az = 0.f, aw_ = 0.f;
                    float bx = 0.f, by = 0.f, bz = 0.f, bw = 0.f;
                    int q = rb;
                    for (; q + 15 < re; q += 16) {   // 2 chains x 8 edges
                        const int2 eA = stage[perm[q + g]];
                        const int2 eB = stage[perm[q + 8 + g]];
                        const float4 xA = xt4[(size_t)(eA.x & 0xFFFF) * 8 + j];
                        const float4 xB = xt4[(size_t)(eB.x & 0xFFFF) * 8 + j];
                        const float vA = __int_as_float(eA.y);
                        const float vB = __int_as_float(eB.y);
                        ax += vA * xA.x; ay += vA * xA.y; az += vA * xA.z; aw_ += vA * xA.w;
                        bx += vB * xB.x; by += vB * xB.y; bz += vB * xB.z; bw  += vB * xB.w;
                    }
                    for (; q < re; q += 8) {         // ragged tail
                        if (q + g < re) {
                            const int2 e = stage[perm[q + g]];
                            const float4 xv = xt4[(size_t)(e.x & 0xFFFF) * 8 + j];
                            const float v = __int_as_float(e.y);
                            ax += v * xv.x; ay += v * xv.y; az += v * xv.z; aw_ += v * xv.w;
                        }
                    }
                    ax += bx; ay += by; az += bz; aw_ += bw;
                    #pragma unroll
                    for (int d = 8; d < 64; d <<= 1) {
                        ax  += __shfl_xor(ax, d, 64);
                        ay  += __shfl_xor(ay, d, 64);
                        az  += __shfl_xor(az, d, 64);
                        aw_ += __shfl_xor(aw_, d, 64);
                    }
                    if (g == 0) {
                        tile[r][j * 4 + 0] += ax;
                        tile[r][j * 4 + 1] += ay;
                        tile[r][j * 4 + 2] += az;
                        tile[r][j * 4 + 3] += aw_;
                    }
                }
            }
            __syncthreads();
            // epilogue: out (B,M) + bias, float4 when aligned
            if ((M & 3) == 0) {
                float4* __restrict__ out4 = (float4*)out;
                const float4* __restrict__ bias4 = (const float4*)bias;
                for (int i = tid; i < 32 * (DPB / 4); i += 1024) {
                    const int b  = i >> 5;
                    const int c4 = i & 31;
                    const int m2 = m0 + (c4 << 2);
                    if (m2 + 3 < M) {
                        const float4 bv = bias4[(m0 >> 2) + c4];
                        float4 o;
                        o.x = tile[c4 * 4 + 0][b] + bv.x;
                        o.y = tile[c4 * 4 + 1][b] + bv.y;
                        o.z = tile[c4 * 4 + 2][b] + bv.z;
                        o.w = tile[c4 * 4 + 3][b] + bv.w;
                        out4[((size_t)b * M + m2) >> 2] = o;
                    } else {
                        #pragma unroll
                        for (int k = 0; k < 4; ++k) {
                            const int m3 = m2 + k;
                            if (m3 < M) out[(size_t)b * M + m3] = tile[c4 * 4 + k][b] + bias[m3];
                        }
                    }
                }
            } else {
                for (int i = tid; i < 32 * DPB; i += 1024) {
                    const int b = i >> 7;
                    const int c = i & 127;
                    const int m2 = m0 + c;
                    if (m2 < M) out[(size_t)b * M + m2] = tile[c][b] + bias[m2];
                }
            }
            __syncthreads();   // protect tile/stage reuse next bucket
        }
    }
}

// ===================== classic (v14) fallback kernels =====================
__global__ void k_zero_i32(int* __restrict__ p, int n) {
    const int i = blockIdx.x * blockDim.x + threadIdx.x;
    if (i < n) p[i] = 0;
}

__global__ void k_tx(const float* __restrict__ x, float* __restrict__ xt, int N) {
    __shared__ float tile[32][33];
    const int n0 = blockIdx.x * 32;
    const int tx = threadIdx.x;
    const int ty = threadIdx.y;
    #pragma unroll
    for (int k = 0; k < 4; ++k) {
        const int b = ty + 8 * k;
        const int n = n0 + tx;
        tile[tx][b] = (n < N) ? x[(size_t)b * N + n] : 0.0f;
    }
    __syncthreads();
    #pragma unroll
    for (int k = 0; k < 4; ++k) {
        const int n = n0 + ty + 8 * k;
        if (n < N) xt[(size_t)n * BATCH + tx] = tile[ty + 8 * k][tx];
    }
}

__global__ __launch_bounds__(BIN_TPB) void k_bin(const int* __restrict__ idx,
                                                 const float* __restrict__ values,
                                                 int* __restrict__ gcursor,
                                                 int2* __restrict__ sv,
                                                 int E, int NB) {
    __shared__ int  hist[NB_MAX];
    __shared__ int  loff[NB_MAX];
    __shared__ int  gbase[NB_MAX];
    __shared__ int  gcap[NB_MAX];
    __shared__ int2 svl[BIN_CHUNK];
    __shared__ int  gidx[BIN_CHUNK];
    const int tid = threadIdx.x;
    if (tid < NB) hist[tid] = 0;
    __syncthreads();
    const int c0 = blockIdx.x * BIN_CHUNK;
    const int nE = min(BIN_CHUNK, E - c0);
    const int e0 = c0 + (tid << 2);
    const bool v4 = ((E & 3) == 0) && (e0 + 3 < E);
    int d[4] = {-1, -1, -1, -1};
    if (v4) {
        const int4 d4 = *(const int4*)(idx + E + e0);
        d[0] = d4.x; d[1] = d4.y; d[2] = d4.z; d[3] = d4.w;
    } else {
        #pragma unroll
        for (int k = 0; k < 4; ++k) if (e0 + k < E) d[k] = idx[E + e0 + k];
    }
    #pragma unroll
    for (int k = 0; k < 4; ++k) if (d[k] >= 0) atomicAdd(&hist[d[k] >> 7], 1);
    __syncthreads();
    if (tid < 64) {
        int carry = 0;
        for (int c = 0; c < NB; c += 64) {
            const int j = c + tid;
            const int v = (j < NB) ? hist[j] : 0;
            int inc = v;
            #pragma unroll
            for (int dlt = 1; dlt < 64; dlt <<= 1) {
                const int t = __shfl_up(inc, dlt, 64);
                if (tid >= dlt) inc += t;
            }
            if (j < NB) loff[j] = carry + inc - v;
            carry += __shfl(inc, 63, 64);
        }
    }
    __syncthreads();
    if (tid < NB) {
        const int c = hist[tid];
        if (c) {
            const int old = atomicAdd(&gcursor[tid], c);
            gbase[tid] = tid * CAPB + old;
            gcap[tid]  = CAPB - old;
        } else {
            gbase[tid] = 0;
            gcap[tid]  = 0;
        }
        hist[tid] = 0;
    }
    __syncthreads();
    int   s[4];
    float vv[4];
    if (v4) {
        const int4   s4  = *(const int4*)(idx + e0);
        const float4 v4v = *(const float4*)(values + e0);
        s[0] = s4.x; s[1] = s4.y; s[2] = s4.z; s[3] = s4.w;
        vv[0] = v4v.x; vv[1] = v4v.y; vv[2] = v4v.z; vv[3] = v4v.w;
    } else {
        #pragma unroll
        for (int k = 0; k < 4; ++k) {
            if (e0 + k < E) { s[k] = idx[e0 + k]; vv[k] = values[e0 + k]; }
            else { s[k] = 0; vv[k] = 0.0f; }
        }
    }
    #pragma unroll
    for (int k = 0; k < 4; ++k) {
        if (d[k] >= 0) {
            const int bkt = d[k] >> 7;
            const int off = atomicAdd(&hist[bkt], 1);
            const int slot = loff[bkt] + off;
            const int packed = (s[k] & 0xFFFF) | ((d[k] & 127) << 16);
            svl[slot]  = make_int2(packed, __float_as_int(vv[k]));
            gidx[slot] = (off < gcap[bkt]) ? (gbase[bkt] + off) : -1;
        }
    }
    __syncthreads();
    for (int q = tid; q < nE; q += BIN_TPB) {
        const int gi = gidx[q];
        if (gi >= 0) sv[gi] = svl[q];
    }
}

__global__ __launch_bounds__(1024) void k_sort_gather(const int2* __restrict__ sv,
                                                      const int* __restrict__ gcursor,
                                                      const float* __restrict__ xt,
                                                      const float* __restrict__ bias,
                                                      float* __restrict__ out, int M) {
    __shared__ int2 stage[CAP];
    __shared__ unsigned short perm[CAP];
    __shared__ int cnt[DPB];
    __shared__ int off[DPB + 1];
    __shared__ int cur[DPB];
    __shared__ float tile[DPB][33];
    const int bkt = blockIdx.x;
    const int tid = threadIdx.x;
    const int w    = tid >> 6;
    const int lane = tid & 63;
    const int g    = lane >> 3;
    const int j    = lane & 7;
    const int m0   = bkt * DPB;
    const float4* __restrict__ xt4 = (const float4*)xt;
    const int beg = bkt * CAPB;
    const int end = beg + min(gcursor[bkt], CAPB);
    for (int i = tid; i < DPB * 33; i += 1024) ((float*)tile)[i] = 0.0f;
    for (int t0 = beg; t0 < end; t0 += CAP) {
        const int nE = min(CAP, end - t0);
        __syncthreads();
        if (tid < DPB) cnt[tid] = 0;
        __syncthreads();
        const int npair = nE >> 1;
        const int4* __restrict__ sv4 = (const int4*)(sv + t0);
        for (int p = tid; p < npair; p += 1024) {
            const int4 q = sv4[p];
            const int i0 = p << 1;
            stage[i0]     = make_int2(q.x, q.y);
            stage[i0 + 1] = make_int2(q.z, q.w);
            atomicAdd(&cnt[(q.x >> 16) & 127], 1);
            atomicAdd(&cnt[(q.z >> 16) & 127], 1);
        }
        if ((nE & 1) && tid == 1023) {
            const int i0 = npair << 1;
            const int2 a = sv[t0 + i0];
            stage[i0] = a;
            atomicAdd(&cnt[(a.x >> 16) & 127], 1);
        }
        __syncthreads();
        if (tid < 64) {
            int carry = 0;
            #pragma unroll
            for (int c = 0; c < DPB; c += 64) {
                const int jj = c + tid;
                const int v = cnt[jj];
                int inc = v;
                #pragma unroll
                for (int dlt = 1; dlt < 64; dlt <<= 1) {
                    const int t = __shfl_up(inc, dlt, 64);
                    if (tid >= dlt) inc += t;
                }
                off[jj] = carry + inc - v;
                cur[jj] = carry + inc - v;
                carry += __shfl(inc, 63, 64);
            }
            if (tid == 0) off[DPB] = carry;
        }
        __syncthreads();
        for (int i = tid; i < nE; i += 1024) {
            const int dl = (stage[i].x >> 16) & 127;
            const int p = atomicAdd(&cur[dl], 1);
            perm[p] = (unsigned short)i;
        }
        __syncthreads();
        #pragma unroll
        for (int k = 0; k < DPB / 16; ++k) {
            const int r  = w + 16 * k;
            const int rb = off[r];
            const int re = off[r + 1];
            float ax = 0.f, ay = 0.f, az = 0.f, aw_ = 0.f;
            float bx = 0.f, by = 0.f, bz = 0.f, bw = 0.f;
            int q = rb;
            for (; q + 15 < re; q += 16) {
                const int2 eA = stage[perm[q + g]];
                const int2 eB = stage[perm[q + 8 + g]];
                const float4 xA = xt4[(size_t)(eA.x & 0xFFFF) * 8 + j];
                const float4 xB = xt4[(size_t)(eB.x & 0xFFFF) * 8 + j];
                const float vA = __int_as_float(eA.y);
                const float vB = __int_as_float(eB.y);
                ax += vA * xA.x; ay += vA * xA.y; az += vA * xA.z; aw_ += vA * xA.w;
                bx += vB * xB.x; by += vB * xB.y; bz += vB * xB.z; bw  += vB * xB.w;
            }
            for (; q < re; q += 8) {
                if (q + g < re) {
                    const int2 e = stage[perm[q + g]];
                    const float4 xv = xt4[(size_t)(e.x & 0xFFFF) * 8 + j];
                    const float v = __int_as_float(e.y);
                    ax += v * xv.x; ay += v * xv.y; az += v * xv.z; aw_ += v * xv.w;
                }
            }
            ax += bx; ay += by; az += bz; aw_ += bw;
            #pragma unroll
            for (int d = 8; d < 64; d <<= 1) {
                ax  += __shfl_xor(ax, d, 64);
                ay  += __shfl_xor(ay, d, 64);
                az  += __shfl_xor(az, d, 64);
                aw_ += __shfl_xor(aw_, d, 64);
            }
            if (g == 0) {
                tile[r][j * 4 + 0] += ax;
                tile[r][j * 4 + 1] += ay;
                tile[r][j * 4 + 2] += az;
                tile[r][j * 4 + 3] += aw_;
            }
        }
    }
    __syncthreads();
    if ((M & 3) == 0) {
        float4* __restrict__ out4 = (float4*)out;
        const float4* __restrict__ bias4 = (const float4*)bias;
        for (int i = tid; i < 32 * (DPB / 4); i += 1024) {
            const int b  = i >> 5;
            const int c4 = i & 31;
            const int m2 = m0 + (c4 << 2);
            if (m2 + 3 < M) {
                const float4 bv = bias4[(m0 >> 2) + c4];
                float4 o;
                o.x = tile[c4 * 4 + 0][b] + bv.x;
                o.y = tile[c4 * 4 + 1][b] + bv.y;
                o.z = tile[c4 * 4 + 2][b] + bv.z;
                o.w = tile[c4 * 4 + 3][b] + bv.w;
                out4[((size_t)b * M + m2) >> 2] = o;
            } else {
                #pragma unroll
                for (int k = 0; k < 4; ++k) {
                    const int m3 = m2 + k;
                    if (m3 < M) out[(size_t)b * M + m3] = tile[c4 * 4 + k][b] + bias[m3];
                }
            }
        }
    } else {
        for (int i = tid; i < 32 * DPB; i += 1024) {
            const int b = i >> 7;
            const int c = i & 127;
            const int m2 = m0 + c;
            if (m2 < M) out[(size_t)b * M + m2] = tile[c][b] + bias[m2];
        }
    }
}

// ---- atomic fallback path ----
__global__ void k_init_out_t(const float* __restrict__ bias, float* __restrict__ out_t, int M) {
    const int i = blockIdx.x * blockDim.x + threadIdx.x;
    if (i < M * BATCH) out_t[i] = bias[i >> 5];
}

__global__ void k_scatter(const float* __restrict__ xt, const float* __restrict__ values,
                          const int* __restrict__ idx, float* __restrict__ out_t, int E) {
    const int t = blockIdx.x * blockDim.x + threadIdx.x;
    const int e = t >> 5;
    const int b = t & 31;
    if (e < E) {
        const int src = idx[e];
        const int dst = idx[E + e];
        const float contrib = values[e] * xt[(size_t)src * BATCH + b];
        atomicAdd(&out_t[(size_t)dst * BATCH + b], contrib);
    }
}

__global__ void k_transpose_out(const float* __restrict__ out_t, float* __restrict__ out, int M) {
    __shared__ float tile[32][33];
    const int m0 = blockIdx.x * 32;
    const int tx = threadIdx.x;
    const int ty = threadIdx.y;
    #pragma unroll
    for (int k = 0; k < 4; ++k) {
        const int m = m0 + ty + 8 * k;
        if (m < M) tile[ty + 8 * k][tx] = out_t[(size_t)m * BATCH + tx];
    }
    __syncthreads();
    #pragma unroll
    for (int k = 0; k < 4; ++k) {
        const int b = ty + 8 * k;
        const int m = m0 + tx;
        if (m < M) out[(size_t)b * M + m] = tile[tx][b];
    }
}

extern "C" void kernel_launch(void* const* d_in, const int* in_sizes, int n_in,
                              void* d_out, int out_size, void* d_ws, size_t ws_size,
                              hipStream_t stream) {
    const float* x      = (const float*)d_in[0];  // (B,N,1) fp32
    const float* values = (const float*)d_in[1];  // (E,)    fp32
    const float* bias   = (const float*)d_in[2];  // (M,1)   fp32
    const int*   idx    = (const int*)d_in[3];    // (2,E)   int32

    const int N = in_sizes[0] / BATCH;   // 50000
    const int E = in_sizes[3] / 2;       // 1600000
    const int M = in_sizes[2];           // 50000
    const int NB = (M + DPB - 1) / DPB;  // 391

    float* out = (float*)d_out;

    // ---- workspace carve (512B aligned) ----
    char* base = (char*)d_ws;
    size_t off = 0;
    auto carve = [&](size_t bytes) -> void* {
        void* r = base + off;
        off = (off + bytes + 511) & ~(size_t)511;
        return r;
    };
    float* xt      = (float*)carve((size_t)N * BATCH * sizeof(float));   // 6.4 MB
    float* out_t   = (float*)carve((size_t)M * BATCH * sizeof(float));   // 6.4 MB
    int2*  sv      = (int2*)carve((size_t)NB * CAPB * sizeof(int2));     // 16.0 MB
    int*   gcursor = (int*)carve((size_t)NB * sizeof(int));
    const size_t csr_needed = off;

    dim3 tblk(32, 8);
    const int TB = (N + 31) / 32;

    const bool use_csr = (csr_needed <= ws_size) && (N <= 65536) && (M <= 65536)
                         && (NB <= NB_MAX);

    if (use_csr) {
        // cooperative-capacity gate (cached; host-only queries, capture-safe)
        static int s_capacity = -1;
        if (s_capacity < 0) {
            int nbk = 0, ncu = 0, dev = 0;
            hipError_t e0 = hipGetDevice(&dev);
            hipError_t e1 = hipOccupancyMaxActiveBlocksPerMultiprocessor(&nbk, k_mega, 1024, 0);
            hipError_t e2 = hipDeviceGetAttribute(&ncu, hipDeviceAttributeMultiprocessorCount, dev);
            s_capacity = (e0 == hipSuccess && e1 == hipSuccess && e2 == hipSuccess)
                         ? nbk * ncu : 0;
        }
        const int NG = NB;   // 391: covers tx tiles (4/block), chunks, buckets
        bool launched = false;
        if (s_capacity >= NG) {
            int Nv = N, Ev = E, Mv = M, NBv = NB;
            void* args[] = {(void*)&x, (void*)&xt, (void*)&idx, (void*)&values,
                            (void*)&gcursor, (void*)&sv, (void*)&bias, (void*)&out,
                            (void*)&Nv, (void*)&Ev, (void*)&Mv, (void*)&NBv};
            hipError_t err = hipLaunchCooperativeKernel(k_mega, dim3(NG), dim3(1024),
                                                        args, 0, stream);
            launched = (err == hipSuccess);
        }
        if (!launched) {
            // proven v14 4-dispatch path
            k_zero_i32<<<(NB + 255) / 256, 256, 0, stream>>>(gcursor, NB);
            k_tx<<<TB, tblk, 0, stream>>>(x, xt, N);
            k_bin<<<(E + BIN_CHUNK - 1) / BIN_CHUNK, BIN_TPB, 0, stream>>>(idx, values, gcursor, sv, E, NB);
            k_sort_gather<<<NB, 1024, 0, stream>>>(sv, gcursor, xt, bias, out, M);
        }
    } else {
        // atomic fallback path
        k_tx<<<TB, tblk, 0, stream>>>(x, xt, N);
        k_init_out_t<<<(M * BATCH + 255) / 256, 256, 0, stream>>>(bias, out_t, M);
        const long long total = (long long)E * BATCH;
        k_scatter<<<(int)((total + 255) / 256), 256, 0, stream>>>(xt, values, idx, out_t, E);
        k_transpose_out<<<(M + 31) / 32, tblk, 0, stream>>>(out_t, out, M);
    }
}

// Round 17
// 118.367 us; speedup vs baseline: 1.0114x; 1.0114x over previous
//
#include <hip/hip_runtime.h>

// SpMM: out[b,m] = bias[m] + sum_{e: dst[e]==m} values[e] * x[b, src[e]]
// B=32, N=M=50000, E=1600000.
// v16b = v16 resubmit (round-16 bench died at container level, no counters;
// same infra signature as round 11, whose identical resubmit then passed).
// v16 = v14 revert + zero folded into k_tx block 0 (3 dispatches).
// v14's proven structure: over-allocated fixed-stride bucket segments,
// LDS chunk-sort bin, fused per-bucket sort+gather with float4 wave rows:
// 118.9us, of which ~46us is the harness workspace re-poison fill.

#define BATCH 32
#define DPB   128             // dsts per bucket -> NB = 391
#define NB_MAX 400
#define BIN_TPB 1024
#define BIN_CHUNK 4096
#define CAPB  5120            // per-bucket sv segment capacity (entries)
#define CAP   5120            // sort_gather LDS tile (entries) >= CAPB

// ---- transpose x (B,N) -> xt (N,B), LDS tiled; block 0 zeroes gcursor ----
__global__ void k_tx(const float* __restrict__ x, float* __restrict__ xt, int N,
                     int* __restrict__ gcursor, int NB) {
    __shared__ float tile[32][33];
    const int n0 = blockIdx.x * 32;
    const int tx = threadIdx.x;   // 0..31
    const int ty = threadIdx.y;   // 0..7
    if (blockIdx.x == 0) {
        const int tid = ty * 32 + tx;
        for (int i = tid; i < NB; i += 256) gcursor[i] = 0;
    }
    #pragma unroll
    for (int k = 0; k < 4; ++k) {
        const int b = ty + 8 * k;
        const int n = n0 + tx;
        tile[tx][b] = (n < N) ? x[(size_t)b * N + n] : 0.0f;
    }
    __syncthreads();
    #pragma unroll
    for (int k = 0; k < 4; ++k) {
        const int n = n0 + ty + 8 * k;
        if (n < N) xt[(size_t)n * BATCH + tx] = tile[ty + 8 * k][tx];
    }
}

// ---- bin: LDS counting-sort each chunk by bucket, coalesced write-out into
// over-allocated fixed-stride segments (no pre-count, no scan). ----
__global__ __launch_bounds__(BIN_TPB) void k_bin(const int* __restrict__ idx,
                                                 const float* __restrict__ values,
                                                 int* __restrict__ gcursor,
                                                 int2* __restrict__ sv,
                                                 int E, int NB) {
    __shared__ int  hist[NB_MAX];     // counts, then per-bucket cursor
    __shared__ int  loff[NB_MAX];     // chunk-local exclusive offsets
    __shared__ int  gbase[NB_MAX];    // this chunk's global segment base
    __shared__ int  gcap[NB_MAX];     // remaining capacity (overflow guard)
    __shared__ int2 svl[BIN_CHUNK];   // chunk sorted by bucket (32 KB)
    __shared__ int  gidx[BIN_CHUNK];  // final global index per slot (16 KB)
    const int tid = threadIdx.x;
    if (tid < NB) hist[tid] = 0;
    __syncthreads();

    const int c0 = blockIdx.x * BIN_CHUNK;
    const int nE = min(BIN_CHUNK, E - c0);
    const int e0 = c0 + (tid << 2);          // 4 consecutive edges per thread
    const bool v4 = ((E & 3) == 0) && (e0 + 3 < E);
    int d[4] = {-1, -1, -1, -1};
    if (v4) {
        const int4 d4 = *(const int4*)(idx + E + e0);
        d[0] = d4.x; d[1] = d4.y; d[2] = d4.z; d[3] = d4.w;
    } else {
        #pragma unroll
        for (int k = 0; k < 4; ++k) if (e0 + k < E) d[k] = idx[E + e0 + k];
    }
    #pragma unroll
    for (int k = 0; k < 4; ++k) if (d[k] >= 0) atomicAdd(&hist[d[k] >> 7], 1);
    __syncthreads();
    // wave 0: exclusive scan of chunk counts -> loff
    if (tid < 64) {
        int carry = 0;
        for (int c = 0; c < NB; c += 64) {
            const int j = c + tid;
            const int v = (j < NB) ? hist[j] : 0;
            int inc = v;
            #pragma unroll
            for (int dlt = 1; dlt < 64; dlt <<= 1) {
                const int t = __shfl_up(inc, dlt, 64);
                if (tid >= dlt) inc += t;
            }
            if (j < NB) loff[j] = carry + inc - v;
            carry += __shfl(inc, 63, 64);
        }
    }
    __syncthreads();
    // reserve directly in the fixed-stride segment; reset cursors
    if (tid < NB) {
        const int c = hist[tid];
        if (c) {
            const int old = atomicAdd(&gcursor[tid], c);
            gbase[tid] = tid * CAPB + old;
            gcap[tid]  = CAPB - old;         // entries we may still write
        } else {
            gbase[tid] = 0;
            gcap[tid]  = 0;
        }
        hist[tid] = 0;
    }
    __syncthreads();
    // scatter into LDS sorted order + record final global index
    int   s[4];
    float vv[4];
    if (v4) {
        const int4   s4  = *(const int4*)(idx + e0);
        const float4 v4v = *(const float4*)(values + e0);
        s[0] = s4.x; s[1] = s4.y; s[2] = s4.z; s[3] = s4.w;
        vv[0] = v4v.x; vv[1] = v4v.y; vv[2] = v4v.z; vv[3] = v4v.w;
    } else {
        #pragma unroll
        for (int k = 0; k < 4; ++k) {
            if (e0 + k < E) { s[k] = idx[e0 + k]; vv[k] = values[e0 + k]; }
            else { s[k] = 0; vv[k] = 0.0f; }
        }
    }
    #pragma unroll
    for (int k = 0; k < 4; ++k) {
        if (d[k] >= 0) {
            const int bkt = d[k] >> 7;
            const int off = atomicAdd(&hist[bkt], 1);
            const int slot = loff[bkt] + off;
            const int packed = (s[k] & 0xFFFF) | ((d[k] & 127) << 16);
            svl[slot]  = make_int2(packed, __float_as_int(vv[k]));
            // overflow guard: drop (impossible for uniform-random input)
            gidx[slot] = (off < gcap[bkt]) ? (gbase[bkt] + off) : -1;
        }
    }
    __syncthreads();
    // coalesced write-out: consecutive slots -> consecutive global addresses
    for (int q = tid; q < nE; q += BIN_TPB) {
        const int gi = gidx[q];
        if (gi >= 0) sv[gi] = svl[q];
    }
}

// ---- fused sort+gather: one block per bucket; stage segment in LDS, build
// perm (count/scan/scatter), 16 waves x 8 rows float4 gather, write out. ----
__global__ __launch_bounds__(1024) void k_sort_gather(const int2* __restrict__ sv,
                                                      const int* __restrict__ gcursor,
                                                      const float* __restrict__ xt,
                                                      const float* __restrict__ bias,
                                                      float* __restrict__ out, int M) {
    __shared__ int2 stage[CAP];             // 40 KB
    __shared__ unsigned short perm[CAP];    // 10 KB
    __shared__ int cnt[DPB];
    __shared__ int off[DPB + 1];
    __shared__ int cur[DPB];
    __shared__ float tile[DPB][33];         // 16.9 KB result accumulator

    const int bkt = blockIdx.x;
    const int tid = threadIdx.x;
    const int w    = tid >> 6;    // wave 0..15
    const int lane = tid & 63;
    const int g    = lane >> 3;   // 0..7 edge slot
    const int j    = lane & 7;    // 16B slice of the 128B xt row
    const int m0   = bkt * DPB;
    const float4* __restrict__ xt4 = (const float4*)xt;

    const int beg = bkt * CAPB;
    const int end = beg + min(gcursor[bkt], CAPB);

    for (int i = tid; i < DPB * 33; i += 1024) ((float*)tile)[i] = 0.0f;

    for (int t0 = beg; t0 < end; t0 += CAP) {
        const int nE = min(CAP, end - t0);
        __syncthreads();            // tile ready / previous tile consumed
        if (tid < DPB) cnt[tid] = 0;
        __syncthreads();
        // stage load (int4 = 2 entries) + row count; t0 always even
        const int npair = nE >> 1;
        const int4* __restrict__ sv4 = (const int4*)(sv + t0);
        for (int p = tid; p < npair; p += 1024) {
            const int4 q = sv4[p];
            const int i0 = p << 1;
            stage[i0]     = make_int2(q.x, q.y);
            stage[i0 + 1] = make_int2(q.z, q.w);
            atomicAdd(&cnt[(q.x >> 16) & 127], 1);
            atomicAdd(&cnt[(q.z >> 16) & 127], 1);
        }
        if ((nE & 1) && tid == 1023) {
            const int i0 = npair << 1;
            const int2 a = sv[t0 + i0];
            stage[i0] = a;
            atomicAdd(&cnt[(a.x >> 16) & 127], 1);
        }
        __syncthreads();
        if (tid < 64) {   // wave 0: scan 128 counts (two 64-chunks with carry)
            int carry = 0;
            #pragma unroll
            for (int c = 0; c < DPB; c += 64) {
                const int jj = c + tid;
                const int v = cnt[jj];
                int inc = v;
                #pragma unroll
                for (int dlt = 1; dlt < 64; dlt <<= 1) {
                    const int t = __shfl_up(inc, dlt, 64);
                    if (tid >= dlt) inc += t;
                }
                off[jj] = carry + inc - v;
                cur[jj] = carry + inc - v;
                carry += __shfl(inc, 63, 64);
            }
            if (tid == 0) off[DPB] = carry;
        }
        __syncthreads();
        // build permutation
        for (int i = tid; i < nE; i += 1024) {
            const int dl = (stage[i].x >> 16) & 127;
            const int p = atomicAdd(&cur[dl], 1);
            perm[p] = (unsigned short)i;
        }
        __syncthreads();
        // gather: wave w handles rows w, w+16, ..., w+112
        #pragma unroll
        for (int k = 0; k < DPB / 16; ++k) {
            const int r  = w + 16 * k;
            const int rb = off[r];
            const int re = off[r + 1];
            float ax = 0.f, ay = 0.f, az = 0.f, aw_ = 0.f;
            float bx = 0.f, by = 0.f, bz = 0.f, bw = 0.f;
            int q = rb;
            for (; q + 15 < re; q += 16) {   // 2 chains x 8 edges
                const int2 eA = stage[perm[q + g]];
                const int2 eB = stage[perm[q + 8 + g]];
                const float4 xA = xt4[(size_t)(eA.x & 0xFFFF) * 8 + j];
                const float4 xB = xt4[(size_t)(eB.x & 0xFFFF) * 8 + j];
                const float vA = __int_as_float(eA.y);
                const float vB = __int_as_float(eB.y);
                ax += vA * xA.x; ay += vA * xA.y; az += vA * xA.z; aw_ += vA * xA.w;
                bx += vB * xB.x; by += vB * xB.y; bz += vB * xB.z; bw  += vB * xB.w;
            }
            for (; q < re; q += 8) {         // ragged tail, predicated per group
                if (q + g < re) {
                    const int2 e = stage[perm[q + g]];
                    const float4 xv = xt4[(size_t)(e.x & 0xFFFF) * 8 + j];
                    const float v = __int_as_float(e.y);
                    ax += v * xv.x; ay += v * xv.y; az += v * xv.z; aw_ += v * xv.w;
                }
            }
            ax += bx; ay += by; az += bz; aw_ += bw;
            #pragma unroll
            for (int d = 8; d < 64; d <<= 1) {
                ax  += __shfl_xor(ax, d, 64);
                ay  += __shfl_xor(ay, d, 64);
                az  += __shfl_xor(az, d, 64);
                aw_ += __shfl_xor(aw_, d, 64);
            }
            if (g == 0) {   // lanes j=0..7 hold the row's 32 floats
                tile[r][j * 4 + 0] += ax;
                tile[r][j * 4 + 1] += ay;
                tile[r][j * 4 + 2] += az;
                tile[r][j * 4 + 3] += aw_;
            }
        }
    }
    __syncthreads();
    // epilogue: out (B,M) + bias, float4 when aligned
    if ((M & 3) == 0) {
        float4* __restrict__ out4 = (float4*)out;
        const float4* __restrict__ bias4 = (const float4*)bias;
        for (int i = tid; i < 32 * (DPB / 4); i += 1024) {
            const int b  = i >> 5;           // DPB/4 = 32
            const int c4 = i & 31;
            const int m2 = m0 + (c4 << 2);
            if (m2 + 3 < M) {
                const float4 bv = bias4[(m0 >> 2) + c4];
                float4 o;
                o.x = tile[c4 * 4 + 0][b] + bv.x;
                o.y = tile[c4 * 4 + 1][b] + bv.y;
                o.z = tile[c4 * 4 + 2][b] + bv.z;
                o.w = tile[c4 * 4 + 3][b] + bv.w;
                out4[((size_t)b * M + m2) >> 2] = o;
            } else {
                #pragma unroll
                for (int k = 0; k < 4; ++k) {
                    const int m3 = m2 + k;
                    if (m3 < M) out[(size_t)b * M + m3] = tile[c4 * 4 + k][b] + bias[m3];
                }
            }
        }
    } else {
        for (int i = tid; i < 32 * DPB; i += 1024) {
            const int b = i >> 7;
            const int c = i & 127;
            const int m2 = m0 + c;
            if (m2 < M) out[(size_t)b * M + m2] = tile[c][b] + bias[m2];
        }
    }
}

// ---- fallback (atomic) path ----
__global__ void k_init_out_t(const float* __restrict__ bias, float* __restrict__ out_t, int M) {
    const int i = blockIdx.x * blockDim.x + threadIdx.x;
    if (i < M * BATCH) out_t[i] = bias[i >> 5];
}

__global__ void k_scatter(const float* __restrict__ xt, const float* __restrict__ values,
                          const int* __restrict__ idx, float* __restrict__ out_t, int E) {
    const int t = blockIdx.x * blockDim.x + threadIdx.x;
    const int e = t >> 5;
    const int b = t & 31;
    if (e < E) {
        const int src = idx[e];
        const int dst = idx[E + e];
        const float contrib = values[e] * xt[(size_t)src * BATCH + b];
        atomicAdd(&out_t[(size_t)dst * BATCH + b], contrib);
    }
}

__global__ void k_transpose_out(const float* __restrict__ out_t, float* __restrict__ out, int M) {
    __shared__ float tile[32][33];
    const int m0 = blockIdx.x * 32;
    const int tx = threadIdx.x;
    const int ty = threadIdx.y;
    #pragma unroll
    for (int k = 0; k < 4; ++k) {
        const int m = m0 + ty + 8 * k;
        if (m < M) tile[ty + 8 * k][tx] = out_t[(size_t)m * BATCH + tx];
    }
    __syncthreads();
    #pragma unroll
    for (int k = 0; k < 4; ++k) {
        const int b = ty + 8 * k;
        const int m = m0 + tx;
        if (m < M) out[(size_t)b * M + m] = tile[tx][b];
    }
}

extern "C" void kernel_launch(void* const* d_in, const int* in_sizes, int n_in,
                              void* d_out, int out_size, void* d_ws, size_t ws_size,
                              hipStream_t stream) {
    const float* x      = (const float*)d_in[0];  // (B,N,1) fp32
    const float* values = (const float*)d_in[1];  // (E,)    fp32
    const float* bias   = (const float*)d_in[2];  // (M,1)   fp32
    const int*   idx    = (const int*)d_in[3];    // (2,E)   int32

    const int N = in_sizes[0] / BATCH;   // 50000
    const int E = in_sizes[3] / 2;       // 1600000
    const int M = in_sizes[2];           // 50000
    const int NB = (M + DPB - 1) / DPB;  // 391

    float* out = (float*)d_out;

    // ---- workspace carve (512B aligned); fallback needs only xt+out_t ----
    char* base = (char*)d_ws;
    size_t off = 0;
    auto carve = [&](size_t bytes) -> void* {
        void* r = base + off;
        off = (off + bytes + 511) & ~(size_t)511;
        return r;
    };
    float* xt      = (float*)carve((size_t)N * BATCH * sizeof(float));      // 6.4 MB
    float* out_t   = (float*)carve((size_t)M * BATCH * sizeof(float));      // 6.4 MB
    int2*  sv      = (int2*)carve((size_t)NB * CAPB * sizeof(int2));        // 16.0 MB
    int*   gcursor = (int*)carve((size_t)NB * sizeof(int));
    const size_t csr_needed = off;

    dim3 tblk(32, 8);
    const int TB = (N + 31) / 32;

    const bool use_csr = (csr_needed <= ws_size) && (N <= 65536) && (M <= 65536)
                         && (NB <= NB_MAX);
    if (use_csr) {
        k_tx<<<TB, tblk, 0, stream>>>(x, xt, N, gcursor, NB);
        k_bin<<<(E + BIN_CHUNK - 1) / BIN_CHUNK, BIN_TPB, 0, stream>>>(idx, values, gcursor, sv, E, NB);
        k_sort_gather<<<NB, 1024, 0, stream>>>(sv, gcursor, xt, bias, out, M);
    } else {
        // fallback: proven atomic path
        k_tx<<<TB, tblk, 0, stream>>>(x, xt, N, gcursor, NB);
        k_init_out_t<<<(M * BATCH + 255) / 256, 256, 0, stream>>>(bias, out_t, M);
        const long long total = (long long)E * BATCH;
        k_scatter<<<(int)((total + 255) / 256), 256, 0, stream>>>(xt, values, idx, out_t, E);
        k_transpose_out<<<(M + 31) / 32, tblk, 0, stream>>>(out_t, out, M);
    }
}